// Round 1
// baseline (45.202 us; speedup 1.0000x reference)
//
#include <hip/hip_runtime.h>

// MultiVectorFieldModel: per-point routed tiny MLP (17 -> 6 -> 16), 65 models.
// Weights per model flattened to 220 floats = 110 float2 pairs:
//   [0..101]   W1  (i*6+j)        -> pairs 0..50
//   [102..107] b1                 -> pairs 51..53
//   [108..203] W2  (j*16+d)       -> pairs 54..101
//   [204..219] b2                 -> pairs 102..109
// LDS layout: wlds[pair][model] (model-minor) so a wave's random `mid`s
// spread across banks; ds_read_b64 base = mid*8, pair index folds into
// the offset: immediate (max 109*520 = 56680 < 65536).

#define NPTS 1000000
#define NMODELS 65
#define BLOCK 1024

__global__ __launch_bounds__(BLOCK) void mvf_kernel(
    const float* __restrict__ x,
    const float* __restrict__ W1,
    const float* __restrict__ b1,
    const float* __restrict__ W2,
    const float* __restrict__ b2,
    float* __restrict__ out,
    int npts)
{
    __shared__ float2 wlds[110][NMODELS];
    const int tid = threadIdx.x;

    // ---- stage weights into LDS, coalesced float2 loads ----
    // W1: 51 pairs per model
    for (int pg = tid; pg < NMODELS * 51; pg += BLOCK) {
        int m = pg / 51, kp = pg % 51;
        wlds[kp][m] = *(const float2*)(W1 + m * 102 + 2 * kp);
    }
    // b1: 3 pairs per model
    for (int pg = tid; pg < NMODELS * 3; pg += BLOCK) {
        int m = pg / 3, kp = pg % 3;
        wlds[51 + kp][m] = *(const float2*)(b1 + m * 6 + 2 * kp);
    }
    // W2: 48 pairs per model
    for (int pg = tid; pg < NMODELS * 48; pg += BLOCK) {
        int m = pg / 48, kp = pg % 48;
        wlds[54 + kp][m] = *(const float2*)(W2 + m * 96 + 2 * kp);
    }
    // b2: 8 pairs per model
    for (int pg = tid; pg < NMODELS * 8; pg += BLOCK) {
        int m = pg / 8, kp = pg % 8;
        wlds[102 + kp][m] = *(const float2*)(b2 + m * 16 + 2 * kp);
    }
    __syncthreads();

    const int p = blockIdx.x * BLOCK + tid;
    if (p >= npts) return;

    // ---- load x row: 18 floats, rows are 72B (8B-aligned) ----
    float xf[18];
    const float2* xr = (const float2*)(x + (long)p * 18);
    #pragma unroll
    for (int i = 0; i < 9; ++i) {
        float2 v = xr[i];
        xf[2 * i] = v.x;
        xf[2 * i + 1] = v.y;
    }
    const float t = xf[17];
    const int c = (int)xf[16];
    int bucket = (int)floorf(t * 8.0f);
    bucket = bucket < 0 ? 0 : (bucket > 7 ? 7 : bucket);
    const int mid = (c == 0) ? 0 : 1 + (c - 1) * 8 + bucket;

    // xin = [data[0..15], t]
    xf[16] = t;

    // ---- h = relu(xin @ W1 + b1) ----
    float h[6];
    {
        float2 v0 = wlds[51][mid];
        float2 v1 = wlds[52][mid];
        float2 v2 = wlds[53][mid];
        h[0] = v0.x; h[1] = v0.y;
        h[2] = v1.x; h[3] = v1.y;
        h[4] = v2.x; h[5] = v2.y;
    }
    #pragma unroll
    for (int i = 0; i < 17; ++i) {
        float2 a = wlds[i * 3 + 0][mid];
        float2 b = wlds[i * 3 + 1][mid];
        float2 d = wlds[i * 3 + 2][mid];
        const float xi = xf[i];
        h[0] = fmaf(xi, a.x, h[0]);
        h[1] = fmaf(xi, a.y, h[1]);
        h[2] = fmaf(xi, b.x, h[2]);
        h[3] = fmaf(xi, b.y, h[3]);
        h[4] = fmaf(xi, d.x, h[4]);
        h[5] = fmaf(xi, d.y, h[5]);
    }
    #pragma unroll
    for (int j = 0; j < 6; ++j) h[j] = h[j] > 0.0f ? h[j] : 0.0f;

    // ---- out = h @ W2 + b2 ----
    float o[16];
    #pragma unroll
    for (int kp = 0; kp < 8; ++kp) {
        float2 v = wlds[102 + kp][mid];
        o[2 * kp] = v.x;
        o[2 * kp + 1] = v.y;
    }
    #pragma unroll
    for (int j = 0; j < 6; ++j) {
        const float hj = h[j];
        #pragma unroll
        for (int kp = 0; kp < 8; ++kp) {
            float2 v = wlds[54 + j * 8 + kp][mid];
            o[2 * kp]     = fmaf(hj, v.x, o[2 * kp]);
            o[2 * kp + 1] = fmaf(hj, v.y, o[2 * kp + 1]);
        }
    }

    // ---- store: 16 floats = 4 x float4, 64B rows (aligned) ----
    float4* orow = (float4*)(out + (long)p * 16);
    #pragma unroll
    for (int q = 0; q < 4; ++q) {
        orow[q] = make_float4(o[4 * q], o[4 * q + 1], o[4 * q + 2], o[4 * q + 3]);
    }
}

extern "C" void kernel_launch(void* const* d_in, const int* in_sizes, int n_in,
                              void* d_out, int out_size, void* d_ws, size_t ws_size,
                              hipStream_t stream) {
    const float* x  = (const float*)d_in[0];
    const float* W1 = (const float*)d_in[1];
    const float* b1 = (const float*)d_in[2];
    const float* W2 = (const float*)d_in[3];
    const float* b2 = (const float*)d_in[4];
    float* out = (float*)d_out;

    const int npts = in_sizes[0] / 18;
    const int grid = (npts + BLOCK - 1) / BLOCK;
    mvf_kernel<<<grid, BLOCK, 0, stream>>>(x, W1, b1, W2, b2, out, npts);
}